// Round 5
// baseline (125004.138 us; speedup 1.0000x reference)
//
#include <hip/hip_runtime.h>
#include <math.h>

// Problem constants
#define N_PTS   30000
#define DIM     64
#define K_C     500
#define K_PAD   512
#define N_ITERS 1000

// tiling
#define BM 128
#define BN 128
#define NTILE 4            // K_PAD / BN
#define GRIDSZ 235         // ceil(30000/128) blocks; <=256 -> co-resident
#define NTH 256
#define NLANES (GRIDSZ * NTH)

// accumulation decomposition (no global atomics)
#define NACCH 64           // chunks per dim-half
#define NACC  128          // accum blocks = 2 halves * 64 chunks
#define ACC_CHUNK 469      // ceil(30000/64)
#define NCNT 16            // count-histogram blocks (b in [128,144))
#define CNT_CHUNK 1875     // 30000/16

#define NBAR (3 * N_ITERS + 8)
#define READY_MAGIC 0x13579BDF

// fixed-point: exact i32 LDS atomics + fixed-order i64 reduce -> deterministic
#define FPSCALE 262144.0f            // 2^18 ; bound: 469 pts * 8 * 2^18 < 2^31
#define INV_FPSCALE (1.0 / 262144.0)

union SMem {
  struct {
    float As[DIM][BM];               // 32 KB, A-tile (restaged by accum blocks)
    union {
      float Bs[DIM][BN];             // 32 KB
      int hist[K_C];                 // count blocks, after barrier-1
    } u;
  } g;
  int acc[K_C * 32];                 // 62.5 KB, accum blocks, after barrier-1
};                                    // 64 KB total

// Minimal grid barrier: per-instance counter (never reset), release-arrive,
// relaxed spin + acquire fence. Requires all blocks co-resident (coop launch).
__device__ __forceinline__ void grid_barrier(int* cnt) {
  __syncthreads();
  if (threadIdx.x == 0) {
    __threadfence();  // release
    __hip_atomic_fetch_add(cnt, 1, __ATOMIC_RELEASE, __HIP_MEMORY_SCOPE_AGENT);
    while (__hip_atomic_load(cnt, __ATOMIC_RELAXED, __HIP_MEMORY_SCOPE_AGENT) < GRIDSZ)
      __builtin_amdgcn_s_sleep(1);
    __threadfence();  // acquire
  }
  __syncthreads();
}

__global__ __launch_bounds__(NTH, 1) void k_kmeans(
    const float* __restrict__ embeds, const float* __restrict__ init_c,
    float* __restrict__ out,
    float* __restrict__ cents, float* __restrict__ csq,
    float* __restrict__ esq, int* __restrict__ idx,
    float* __restrict__ cntf, int* __restrict__ parts,
    int* __restrict__ cntp, int* __restrict__ barcnt,
    int* __restrict__ ready) {
  __shared__ SMem sm;
  const int tid = threadIdx.x;
  const int b = blockIdx.x;
  const int gid = b * NTH + tid;
  const int lane = tid & 63;
  const int wid_g = gid >> 6;
  const int nw = NLANES / 64;

  // ---------------- barrier-state init (ws poisoned 0xAA each launch) ------
  if (b == 0) {
    for (int i = tid; i < NBAR; i += NTH) barcnt[i] = 0;
    __syncthreads();
    if (tid == 0) {
      __threadfence();
      __hip_atomic_store(ready, READY_MAGIC, __ATOMIC_RELEASE, __HIP_MEMORY_SCOPE_AGENT);
    }
    __syncthreads();
  } else {
    if (tid == 0) {
      while (__hip_atomic_load(ready, __ATOMIC_RELAXED, __HIP_MEMORY_SCOPE_AGENT) != READY_MAGIC)
        __builtin_amdgcn_s_sleep(1);
      __threadfence();
    }
    __syncthreads();
  }
  int bar_i = 0;

  // ---------------- phase 0: init (once) ----------------
  for (int i = gid; i < K_C * DIM; i += NLANES) cents[i] = init_c[i];
  for (int p = wid_g; p < N_PTS; p += nw) {
    float v = embeds[(size_t)p * DIM + lane];
    float s = v * v;
    #pragma unroll
    for (int m = 1; m < 64; m <<= 1) s += __shfl_xor(s, m, 64);
    if (lane == 0) esq[p] = s;
  }
  for (int k = wid_g; k < K_PAD; k += nw) {
    float v = (k < K_C) ? init_c[(size_t)k * DIM + lane] : 0.f;
    float s = v * v;
    #pragma unroll
    for (int m = 1; m < 64; m <<= 1) s += __shfl_xor(s, m, 64);
    if (lane == 0) csq[k] = (k < K_C) ? s : INFINITY;
  }
  grid_barrier(&barcnt[bar_i++]);

  // ---------------- loop-invariant per-block state ----------------
  const int m0 = b * BM;
  const int tx = tid & 15, ty = tid >> 4;

  // stage A (transposed): As[d][m]
  #pragma unroll
  for (int l = 0; l < 8; ++l) {
    int e = tid + l * 256;
    int pl = e >> 4, d4 = e & 15;
    int p = m0 + pl;
    float4 v = make_float4(0.f, 0.f, 0.f, 0.f);
    if (p < N_PTS) v = *reinterpret_cast<const float4*>(embeds + (size_t)p * DIM + d4 * 4);
    sm.g.As[d4 * 4 + 0][pl] = v.x; sm.g.As[d4 * 4 + 1][pl] = v.y;
    sm.g.As[d4 * 4 + 2][pl] = v.z; sm.g.As[d4 * 4 + 3][pl] = v.w;
  }
  float esq_r[8];
  #pragma unroll
  for (int i = 0; i < 8; ++i) {
    int mi = (i < 4) ? (ty * 4 + i) : (64 + ty * 4 + (i - 4));
    int p = m0 + mi;
    esq_r[i] = (p < N_PTS) ? esq[p] : 0.f;
  }

  for (int it = 0; it < N_ITERS; ++it) {
    // ================= assign =================
    float best[8]; int bidx[8];
    #pragma unroll
    for (int i = 0; i < 8; ++i) { best[i] = INFINITY; bidx[i] = 0; }

    for (int t = 0; t < NTILE; ++t) {
      const int n0 = t * BN;
      __syncthreads();
      #pragma unroll
      for (int l = 0; l < 8; ++l) {
        int e2 = tid + l * 256;
        int kl = e2 & 127, d4 = e2 >> 7;
        int k = n0 + kl;
        float4 v = make_float4(0.f, 0.f, 0.f, 0.f);
        if (k < K_C) v = *reinterpret_cast<const float4*>(cents + (size_t)k * DIM + d4 * 4);
        sm.g.u.Bs[d4 * 4 + 0][kl] = v.x; sm.g.u.Bs[d4 * 4 + 1][kl] = v.y;
        sm.g.u.Bs[d4 * 4 + 2][kl] = v.z; sm.g.u.Bs[d4 * 4 + 3][kl] = v.w;
      }
      __syncthreads();

      float acc[8][8];
      #pragma unroll
      for (int i = 0; i < 8; ++i)
        #pragma unroll
        for (int j = 0; j < 8; ++j) acc[i][j] = 0.f;

      #pragma unroll 8
      for (int d = 0; d < DIM; ++d) {
        float4 a0 = *reinterpret_cast<const float4*>(&sm.g.As[d][ty * 4]);
        float4 a1 = *reinterpret_cast<const float4*>(&sm.g.As[d][64 + ty * 4]);
        float4 b0 = *reinterpret_cast<const float4*>(&sm.g.u.Bs[d][tx * 4]);
        float4 b1 = *reinterpret_cast<const float4*>(&sm.g.u.Bs[d][64 + tx * 4]);
        float av[8] = {a0.x, a0.y, a0.z, a0.w, a1.x, a1.y, a1.z, a1.w};
        float bv[8] = {b0.x, b0.y, b0.z, b0.w, b1.x, b1.y, b1.z, b1.w};
        #pragma unroll
        for (int i = 0; i < 8; ++i)
          #pragma unroll
          for (int j = 0; j < 8; ++j)
            acc[i][j] = fmaf(av[i], bv[j], acc[i][j]);
      }

      float4 c0 = *reinterpret_cast<const float4*>(&csq[n0 + tx * 4]);
      float4 c1 = *reinterpret_cast<const float4*>(&csq[n0 + 64 + tx * 4]);
      float cv[8] = {c0.x, c0.y, c0.z, c0.w, c1.x, c1.y, c1.z, c1.w};
      #pragma unroll
      for (int j = 0; j < 8; ++j) {
        int n = n0 + ((j < 4) ? (tx * 4 + j) : (64 + tx * 4 + (j - 4)));
        #pragma unroll
        for (int i = 0; i < 8; ++i) {
          float dd = (esq_r[i] - 2.0f * acc[i][j]) + cv[j];
          if (dd < best[i]) { best[i] = dd; bidx[i] = n; }
        }
      }
    }

    #pragma unroll
    for (int i = 0; i < 8; ++i) {
      float v = best[i]; int bi = bidx[i];
      #pragma unroll
      for (int s = 1; s < 16; s <<= 1) {
        float ov = __shfl_xor(v, s, 64);
        int   oi = __shfl_xor(bi, s, 64);
        if (ov < v || (ov == v && oi < bi)) { v = ov; bi = oi; }
      }
      if (tx == 0) {
        int pl = (i < 4) ? (ty * 4 + i) : (64 + ty * 4 + (i - 4));
        int p = m0 + pl;
        if (p < N_PTS) idx[p] = bi;
      }
    }
    grid_barrier(&barcnt[bar_i++]);   // B1: idx globally visible

    // ================= partial accumulation (no global atomics) ===========
    if (b < NACC) {
      const int h = b & 1, j = b >> 1;
      for (int i = tid; i < K_C * 32; i += NTH) sm.acc[i] = 0;
      __syncthreads();
      const int p0 = j * ACC_CHUNK;
      const int pend = min(p0 + ACC_CHUNK, N_PTS);
      const int sub = tid >> 5, d32 = tid & 31;
      const int dim = h * 32 + d32;
      for (int p = p0 + sub; p < pend; p += 8) {
        int k = idx[p];
        float v = embeds[(size_t)p * DIM + dim];
        int iv = __float2int_rn(v * FPSCALE);
        atomicAdd(&sm.acc[k * 32 + d32], iv);   // LDS atomic: exact, fast
      }
      __syncthreads();
      int* dst = parts + (size_t)(h * NACCH + j) * (K_C * 32);
      for (int i = tid; i < K_C * 32; i += NTH) dst[i] = sm.acc[i];
    } else if (b < NACC + NCNT) {
      const int jj = b - NACC;
      for (int i = tid; i < K_C; i += NTH) sm.g.u.hist[i] = 0;
      __syncthreads();
      const int p0 = jj * CNT_CHUNK;
      for (int p = p0 + tid; p < p0 + CNT_CHUNK; p += NTH)
        atomicAdd(&sm.g.u.hist[idx[p]], 1);
      __syncthreads();
      for (int i = tid; i < K_C; i += NTH) cntp[jj * K_C + i] = sm.g.u.hist[i];
    }
    grid_barrier(&barcnt[bar_i++]);   // B2: partials visible

    // ================= update =================
    if (gid < K_C * DIM) {
      int k = gid >> 6, dim = gid & 63;
      int h = dim >> 5, d32 = dim & 31;
      const int* pp = parts + (size_t)(h * NACCH) * (K_C * 32) + k * 32 + d32;
      long long s = 0;
      #pragma unroll 8
      for (int j = 0; j < NACCH; ++j) s += (long long)pp[(size_t)j * (K_C * 32)];
      int c = 0;
      #pragma unroll
      for (int j = 0; j < NCNT; ++j) c += cntp[j * K_C + k];
      float sum_f = (float)((double)s * INV_FPSCALE);
      float nc = sum_f / ((float)c + 1e-6f);   // matches sums / (counts + EPS)
      cents[gid] = nc;
      float sq = nc * nc;
      #pragma unroll
      for (int m = 1; m < 64; m <<= 1) sq += __shfl_xor(sq, m, 64);
      if (lane == 0) { csq[k] = sq; cntf[k] = (float)c; }
    }
    grid_barrier(&barcnt[bar_i++]);   // B3: new cents/csq visible

    // accum blocks destroyed As -> restage for next iteration's assign
    if (b < NACC) {
      #pragma unroll
      for (int l = 0; l < 8; ++l) {
        int e = tid + l * 256;
        int pl = e >> 4, d4 = e & 15;
        int p = m0 + pl;
        float4 v = make_float4(0.f, 0.f, 0.f, 0.f);
        if (p < N_PTS) v = *reinterpret_cast<const float4*>(embeds + (size_t)p * DIM + d4 * 4);
        sm.g.As[d4 * 4 + 0][pl] = v.x; sm.g.As[d4 * 4 + 1][pl] = v.y;
        sm.g.As[d4 * 4 + 2][pl] = v.z; sm.g.As[d4 * 4 + 3][pl] = v.w;
      }
    }
  }

  // ---------------- final output ----------------
  const int tot = K_C * DIM + N_PTS + K_C;
  for (int i = gid; i < tot; i += NLANES) {
    float v;
    if (i < K_C * DIM) v = cents[i];
    else if (i < K_C * DIM + N_PTS) v = (float)idx[i - K_C * DIM];
    else v = cntf[i - K_C * DIM - N_PTS];
    out[i] = v;
  }
}

// ---------------------------------------------------------------------------
extern "C" void kernel_launch(void* const* d_in, const int* in_sizes, int n_in,
                              void* d_out, int out_size, void* d_ws, size_t ws_size,
                              hipStream_t stream) {
  const float* embeds = (const float*)d_in[0];
  const float* init_c = (const float*)d_in[1];
  float* out = (float*)d_out;

  char* w = (char*)d_ws;
  size_t off = 0;
  auto alloc = [&](size_t bytes) -> void* {
    void* p = w + off;
    off += (bytes + 255) & ~(size_t)255;
    return p;
  };
  float* cents  = (float*)alloc((size_t)K_C * DIM * sizeof(float));
  float* csq    = (float*)alloc((size_t)K_PAD * sizeof(float));
  float* esq    = (float*)alloc((size_t)N_PTS * sizeof(float));
  int*   idx    = (int*)  alloc((size_t)N_PTS * sizeof(int));
  float* cntf   = (float*)alloc((size_t)K_C * sizeof(float));
  int*   parts  = (int*)  alloc((size_t)NACC * (K_C * 32) * sizeof(int));  // 8.2 MB
  int*   cntp   = (int*)  alloc((size_t)NCNT * K_C * sizeof(int));
  int*   barcnt = (int*)  alloc((size_t)NBAR * sizeof(int));
  int*   ready  = (int*)  alloc(256);

  void* args[] = {(void*)&embeds, (void*)&init_c, (void*)&out,
                  (void*)&cents, (void*)&csq, (void*)&esq, (void*)&idx,
                  (void*)&cntf, (void*)&parts, (void*)&cntp,
                  (void*)&barcnt, (void*)&ready};
  hipLaunchCooperativeKernel((void*)k_kmeans, dim3(GRIDSZ), dim3(NTH), args, 0, stream);
}

// Round 6
// 94040.839 us; speedup vs baseline: 1.3293x; 1.3293x over previous
//
#include <hip/hip_runtime.h>
#include <math.h>

// Problem constants
#define N_PTS   30000
#define DIM     64
#define K_C     500
#define K_PAD   512
#define N_ITERS 1000

// tiling
#define BM 128
#define BN 128
#define NTILE 4            // K_PAD / BN
#define GRIDSZ 235         // ceil(30000/128); <=256 -> co-resident (coop launch)
#define NTH 256
#define NLANES (GRIDSZ * NTH)

#define NREP 8             // far-atomic contention replicas
#define NBAR (2 * N_ITERS + 8)
#define READY_MAGIC 0x13579BDF

// fixed-point accumulation: exact u64 far-atomics -> bit-deterministic
#define FPSCALE 16777216.0f          // 2^24
#define INV_FPSCALE (1.0 / 16777216.0)

// ---- agent-scope (device) relaxed atomics: L1/L2-bypassing memory-side ops.
// All cross-block data uses these => no buffer_inv/wbl2 fences needed.
__device__ __forceinline__ void st_f32(float* p, float v) {
  __hip_atomic_store(p, v, __ATOMIC_RELAXED, __HIP_MEMORY_SCOPE_AGENT);
}
__device__ __forceinline__ float ld_f32(const float* p) {
  return __hip_atomic_load(p, __ATOMIC_RELAXED, __HIP_MEMORY_SCOPE_AGENT);
}
__device__ __forceinline__ void st_u64(unsigned long long* p, unsigned long long v) {
  __hip_atomic_store(p, v, __ATOMIC_RELAXED, __HIP_MEMORY_SCOPE_AGENT);
}
__device__ __forceinline__ unsigned long long ld_u64(const unsigned long long* p) {
  return __hip_atomic_load(p, __ATOMIC_RELAXED, __HIP_MEMORY_SCOPE_AGENT);
}
__device__ __forceinline__ void st_i32(int* p, int v) {
  __hip_atomic_store(p, v, __ATOMIC_RELAXED, __HIP_MEMORY_SCOPE_AGENT);
}
__device__ __forceinline__ int ld_i32(const int* p) {
  return __hip_atomic_load(p, __ATOMIC_RELAXED, __HIP_MEMORY_SCOPE_AGENT);
}

union U64F2 { unsigned long long u; float2 f; };

struct SMem {
  float As[DIM][BM];                 // 32 KB, loop-invariant (staged once)
  union {
    float Bs[DIM][BN];               // 32 KB, XOR-swizzled cols: col = kl ^ (d & 28)
    float esq_s[BM];                 // one-time scratch before first Bs staging
    int blkidx[BM];                  // after last tile's Bs reads each iter
  } u;
};                                    // 64 KB total

// Fence-free grid barrier: release only on the counter add (orders prior sc1
// ops; L2 is clean so wbl2 is cheap), relaxed spin, NO acquire-invalidate.
__device__ __forceinline__ void grid_barrier(int* cnt) {
  __syncthreads();
  if (threadIdx.x == 0) {
    __atomic_signal_fence(__ATOMIC_SEQ_CST);
    __hip_atomic_fetch_add(cnt, 1, __ATOMIC_RELEASE, __HIP_MEMORY_SCOPE_AGENT);
    while (__hip_atomic_load(cnt, __ATOMIC_RELAXED, __HIP_MEMORY_SCOPE_AGENT) < GRIDSZ)
      __builtin_amdgcn_s_sleep(1);
    __atomic_signal_fence(__ATOMIC_SEQ_CST);
  }
  __syncthreads();
}

__global__ __launch_bounds__(NTH, 1) void k_kmeans(
    const float* __restrict__ embeds, const float* __restrict__ init_c,
    float* __restrict__ out,
    float* __restrict__ cents, float* __restrict__ csq,
    unsigned long long* __restrict__ gsum, int* __restrict__ gcnt,
    int* __restrict__ barcnt, int* __restrict__ ready) {
  __shared__ SMem sm;
  const int tid = threadIdx.x;
  const int b = blockIdx.x;
  const int gid = b * NTH + tid;
  const int lane = tid & 63;
  const int rep = b & (NREP - 1);

  // ---------------- barrier-state init (ws poisoned 0xAA each launch) ------
  if (b == 0) {
    for (int i = tid; i < NBAR; i += NTH) st_i32(&barcnt[i], 0);
    __syncthreads();
    if (tid == 0)
      __hip_atomic_store(ready, READY_MAGIC, __ATOMIC_RELEASE, __HIP_MEMORY_SCOPE_AGENT);
    __syncthreads();
  } else {
    if (tid == 0) {
      while (__hip_atomic_load(ready, __ATOMIC_RELAXED, __HIP_MEMORY_SCOPE_AGENT) != READY_MAGIC)
        __builtin_amdgcn_s_sleep(1);
    }
    __syncthreads();
  }
  int bar_i = 0;

  // ---------------- phase 0: init (once, all via agent-scope stores) -------
  for (int i = gid; i < K_C * DIM; i += NLANES) st_f32(&cents[i], init_c[i]);
  for (int i = gid; i < NREP * K_C * DIM; i += NLANES) st_u64(&gsum[i], 0ull);
  for (int i = gid; i < NREP * K_C; i += NLANES) st_i32(&gcnt[i], 0);
  {
    const int wid_g = gid >> 6, nw = NLANES / 64;
    for (int k = wid_g; k < K_PAD; k += nw) {
      float v = (k < K_C) ? init_c[(size_t)k * DIM + lane] : 0.f;
      float s = v * v;
      #pragma unroll
      for (int m = 1; m < 64; m <<= 1) s += __shfl_xor(s, m, 64);
      if (lane == 0) st_f32(&csq[k], (k < K_C) ? s : INFINITY);
    }
  }

  // ---------------- loop-invariant per-block state ----------------
  const int m0 = b * BM;
  const int m_cnt = min(BM, N_PTS - m0);
  const int tx = tid & 15, ty = tid >> 4;

  // stage A once (transposed): As[d][m]  (own rows; plain cached loads)
  #pragma unroll
  for (int l = 0; l < 8; ++l) {
    int e = tid + l * 256;
    int pl = e >> 4, d4 = e & 15;
    int p = m0 + pl;
    float4 v = make_float4(0.f, 0.f, 0.f, 0.f);
    if (p < N_PTS) v = *reinterpret_cast<const float4*>(embeds + (size_t)p * DIM + d4 * 4);
    sm.As[d4 * 4 + 0][pl] = v.x; sm.As[d4 * 4 + 1][pl] = v.y;
    sm.As[d4 * 4 + 2][pl] = v.z; sm.As[d4 * 4 + 3][pl] = v.w;
  }
  __syncthreads();
  // block-local e_sq from the LDS A-tile (no cross-block esq buffer)
  if (tid < BM) {
    float s = 0.f;
    #pragma unroll 16
    for (int d = 0; d < DIM; ++d) { float v = sm.As[d][tid]; s = fmaf(v, v, s); }
    sm.u.esq_s[tid] = s;
  }
  __syncthreads();
  float esq_r[8];
  #pragma unroll
  for (int i = 0; i < 8; ++i) {
    int mi = (i < 4) ? (ty * 4 + i) : (64 + ty * 4 + (i - 4));
    esq_r[i] = sm.u.esq_s[mi];
  }

  grid_barrier(&barcnt[bar_i++]);   // init visible

  const int g_acc = tid >> 6;        // 4 groups of 64 lanes for accumulation

  for (int it = 0; it < N_ITERS; ++it) {
    // ================= assign =================
    float best[8]; int bidx[8];
    #pragma unroll
    for (int i = 0; i < 8; ++i) { best[i] = INFINITY; bidx[i] = 0; }

    for (int t = 0; t < NTILE; ++t) {
      const int n0 = t * BN;
      __syncthreads();               // protect previous Bs/esq/blkidx readers
      // stage B tile: coalesced u64 agent loads (2 rows x 256B per wave),
      // LDS cols XOR-swizzled: col = kl ^ (d & 28)  (4-way write conflicts)
      #pragma unroll
      for (int l = 0; l < 16; ++l) {
        int e = tid + l * 256;       // 0..4095
        int dp = e & 31, kl = e >> 5;
        int k = n0 + kl;
        U64F2 w; w.u = 0ull;
        if (k < K_C)
          w.u = ld_u64((const unsigned long long*)cents + (size_t)k * 32 + dp);
        int d0 = dp * 2;
        int col = kl ^ (d0 & 28);
        sm.u.Bs[d0][col] = w.f.x; sm.u.Bs[d0 + 1][col] = w.f.y;
      }
      __syncthreads();

      float acc[8][8];
      #pragma unroll
      for (int i = 0; i < 8; ++i)
        #pragma unroll
        for (int j = 0; j < 8; ++j) acc[i][j] = 0.f;

      #pragma unroll 8
      for (int d = 0; d < DIM; ++d) {
        const int s4 = d & 28;
        float4 a0 = *reinterpret_cast<const float4*>(&sm.As[d][ty * 4]);
        float4 a1 = *reinterpret_cast<const float4*>(&sm.As[d][64 + ty * 4]);
        float4 b0 = *reinterpret_cast<const float4*>(&sm.u.Bs[d][(tx * 4) ^ s4]);
        float4 b1 = *reinterpret_cast<const float4*>(&sm.u.Bs[d][64 + ((tx * 4) ^ s4)]);
        float av[8] = {a0.x, a0.y, a0.z, a0.w, a1.x, a1.y, a1.z, a1.w};
        float bv[8] = {b0.x, b0.y, b0.z, b0.w, b1.x, b1.y, b1.z, b1.w};
        #pragma unroll
        for (int i = 0; i < 8; ++i)
          #pragma unroll
          for (int j = 0; j < 8; ++j)
            acc[i][j] = fmaf(av[i], bv[j], acc[i][j]);
      }

      float cv[8];
      #pragma unroll
      for (int j = 0; j < 8; ++j) {
        int n = n0 + ((j < 4) ? (tx * 4 + j) : (64 + tx * 4 + (j - 4)));
        cv[j] = ld_f32(&csq[n]);
      }
      #pragma unroll
      for (int j = 0; j < 8; ++j) {
        int n = n0 + ((j < 4) ? (tx * 4 + j) : (64 + tx * 4 + (j - 4)));
        #pragma unroll
        for (int i = 0; i < 8; ++i) {
          float dd = (esq_r[i] - 2.0f * acc[i][j]) + cv[j];
          if (dd < best[i]) { best[i] = dd; bidx[i] = n; }
        }
      }
    }

    // cross-lane argmin over 16 tx lanes (registers only)
    #pragma unroll
    for (int i = 0; i < 8; ++i) {
      float v = best[i]; int bi = bidx[i];
      #pragma unroll
      for (int s = 1; s < 16; s <<= 1) {
        float ov = __shfl_xor(v, s, 64);
        int   oi = __shfl_xor(bi, s, 64);
        if (ov < v || (ov == v && oi < bi)) { v = ov; bi = oi; }
      }
      best[i] = v; bidx[i] = bi;
    }

    __syncthreads();                 // all Bs reads done before aliasing with blkidx
    if (tx == 0) {
      #pragma unroll
      for (int i = 0; i < 8; ++i) {
        int pl = (i < 4) ? (ty * 4 + i) : (64 + ty * 4 + (i - 4));
        sm.u.blkidx[pl] = bidx[i];
        int p = m0 + pl;
        if (it == N_ITERS - 1 && p < N_PTS)
          out[K_C * DIM + p] = (float)bidx[i];   // final idx -> out directly
      }
    }
    __syncthreads();

    // ================= accumulate: u64 fixed-point far-atomics =============
    unsigned long long* gs = gsum + (size_t)rep * (K_C * DIM);
    int* gc = gcnt + rep * K_C;
    #pragma unroll 4
    for (int pl = g_acc; pl < m_cnt; pl += 4) {
      int k = sm.u.blkidx[pl];
      float v = embeds[(size_t)(m0 + pl) * DIM + lane];  // warm L2 (no inv!)
      long long iv = __float2ll_rn(v * FPSCALE);
      __hip_atomic_fetch_add(&gs[k * DIM + lane], (unsigned long long)iv,
                             __ATOMIC_RELAXED, __HIP_MEMORY_SCOPE_AGENT);
      if (lane == 0)
        __hip_atomic_fetch_add(&gc[k], 1, __ATOMIC_RELAXED, __HIP_MEMORY_SCOPE_AGENT);
    }
    grid_barrier(&barcnt[bar_i++]);   // B1: sums visible

    // ================= update =================
    if (gid < K_C * DIM) {
      int k = gid >> 6;
      long long s = 0;
      #pragma unroll
      for (int r = 0; r < NREP; ++r) {
        s += (long long)ld_u64(&gsum[(size_t)r * (K_C * DIM) + gid]);
        st_u64(&gsum[(size_t)r * (K_C * DIM) + gid], 0ull);  // re-zero
      }
      int c = 0;
      #pragma unroll
      for (int r = 0; r < NREP; ++r) c += ld_i32(&gcnt[r * K_C + k]);
      float sum_f = (float)((double)s * INV_FPSCALE);
      float nc = sum_f / ((float)c + 1e-6f);   // matches sums / (counts + EPS)
      st_f32(&cents[gid], nc);
      float sq = nc * nc;
      #pragma unroll
      for (int m = 1; m < 64; m <<= 1) sq += __shfl_xor(sq, m, 64);
      if (lane == 0) {
        st_f32(&csq[k], sq);
        #pragma unroll
        for (int r = 0; r < NREP; ++r) st_i32(&gcnt[r * K_C + k], 0);
      }
      if (it == N_ITERS - 1) {
        out[gid] = nc;                              // final centroids
        if (lane == 0) out[K_C * DIM + N_PTS + k] = (float)c;  // final counts
      }
    }
    grid_barrier(&barcnt[bar_i++]);   // B2: new cents/csq visible
  }
}

// ---------------------------------------------------------------------------
extern "C" void kernel_launch(void* const* d_in, const int* in_sizes, int n_in,
                              void* d_out, int out_size, void* d_ws, size_t ws_size,
                              hipStream_t stream) {
  const float* embeds = (const float*)d_in[0];
  const float* init_c = (const float*)d_in[1];
  float* out = (float*)d_out;

  char* w = (char*)d_ws;
  size_t off = 0;
  auto alloc = [&](size_t bytes) -> void* {
    void* p = w + off;
    off += (bytes + 255) & ~(size_t)255;
    return p;
  };
  float*              cents  = (float*)             alloc((size_t)K_C * DIM * sizeof(float));
  float*              csq    = (float*)             alloc((size_t)K_PAD * sizeof(float));
  unsigned long long* gsum   = (unsigned long long*)alloc((size_t)NREP * K_C * DIM * 8);
  int*                gcnt   = (int*)               alloc((size_t)NREP * K_C * sizeof(int));
  int*                barcnt = (int*)               alloc((size_t)NBAR * sizeof(int));
  int*                ready  = (int*)               alloc(256);

  void* args[] = {(void*)&embeds, (void*)&init_c, (void*)&out,
                  (void*)&cents, (void*)&csq, (void*)&gsum, (void*)&gcnt,
                  (void*)&barcnt, (void*)&ready};
  hipLaunchCooperativeKernel((void*)k_kmeans, dim3(GRIDSZ), dim3(NTH), args, 0, stream);
}